// Round 1
// baseline (6761.644 us; speedup 1.0000x reference)
//
#include <hip/hip_runtime.h>
#include <math.h>

#define B_   2048
#define DIN_ 512
#define H_   512
#define E_   512
#define V_   1024
#define L_   32
#define OUTLD (33 * 1024)   // row stride of d_out per batch element

// ---------------- transpose (32x32 LDS tile; all dims here are multiples of 32)
__global__ __launch_bounds__(256) void transpose_k(const float* __restrict__ src,
                                                   float* __restrict__ dst,
                                                   int R, int C) {
    __shared__ float t[32][33];
    const int bc = blockIdx.x * 32, br = blockIdx.y * 32;
    const int tx = threadIdx.x & 31, ty = threadIdx.x >> 5;  // ty in 0..7
    #pragma unroll
    for (int i = 0; i < 32; i += 8)
        t[ty + i][tx] = src[(long)(br + ty + i) * C + bc + tx];
    __syncthreads();
    #pragma unroll
    for (int i = 0; i < 32; i += 8)
        dst[(long)(bc + ty + i) * R + br + tx] = t[tx][ty + i];
}

// ---------------- generic fp32 NT GEMM: C[M,N] = A[M,K]*B[N,K]^T + bias[N]
// tile 64x64, 256 threads, 4x4 per thread. All M,N multiples of 64; K multiple of 16.
#define BK 16
__global__ __launch_bounds__(256) void gemm_nt(const float* __restrict__ A, int lda,
                                               const float* __restrict__ Bm, int ldb,
                                               const float* __restrict__ bias,
                                               float* __restrict__ C, int ldc, int K) {
    __shared__ float As[BK][64 + 4];   // [k][m], row stride 68 floats (16B aligned)
    __shared__ float Bs[BK][64 + 4];   // [k][n]
    const int bm = blockIdx.y * 64;
    const int bn = blockIdx.x * 64;
    const int tid = threadIdx.x;
    const int lr = tid >> 2;           // 0..63 tile row for loading
    const int lk = (tid & 3) << 2;     // 0,4,8,12 k offset for loading
    const float* Ap = A + (long)(bm + lr) * lda + lk;
    const float* Bp = Bm + (long)(bn + lr) * ldb + lk;
    const int tm = (tid & 15) << 2;    // 0..60
    const int tn = (tid >> 4) << 2;    // 0..60
    float acc[4][4] = {};

    for (int k0 = 0; k0 < K; k0 += BK) {
        const float4 av = *(const float4*)(Ap + k0);
        const float4 bv = *(const float4*)(Bp + k0);
        __syncthreads();               // previous tile fully consumed
        As[lk + 0][lr] = av.x; As[lk + 1][lr] = av.y;
        As[lk + 2][lr] = av.z; As[lk + 3][lr] = av.w;
        Bs[lk + 0][lr] = bv.x; Bs[lk + 1][lr] = bv.y;
        Bs[lk + 2][lr] = bv.z; Bs[lk + 3][lr] = bv.w;
        __syncthreads();
        #pragma unroll
        for (int kk = 0; kk < BK; ++kk) {
            const float4 a = *(const float4*)(&As[kk][tm]);
            const float4 b = *(const float4*)(&Bs[kk][tn]);
            acc[0][0] = fmaf(a.x, b.x, acc[0][0]);
            acc[0][1] = fmaf(a.x, b.y, acc[0][1]);
            acc[0][2] = fmaf(a.x, b.z, acc[0][2]);
            acc[0][3] = fmaf(a.x, b.w, acc[0][3]);
            acc[1][0] = fmaf(a.y, b.x, acc[1][0]);
            acc[1][1] = fmaf(a.y, b.y, acc[1][1]);
            acc[1][2] = fmaf(a.y, b.z, acc[1][2]);
            acc[1][3] = fmaf(a.y, b.w, acc[1][3]);
            acc[2][0] = fmaf(a.z, b.x, acc[2][0]);
            acc[2][1] = fmaf(a.z, b.y, acc[2][1]);
            acc[2][2] = fmaf(a.z, b.z, acc[2][2]);
            acc[2][3] = fmaf(a.z, b.w, acc[2][3]);
            acc[3][0] = fmaf(a.w, b.x, acc[3][0]);
            acc[3][1] = fmaf(a.w, b.y, acc[3][1]);
            acc[3][2] = fmaf(a.w, b.z, acc[3][2]);
            acc[3][3] = fmaf(a.w, b.w, acc[3][3]);
        }
    }
    float4 bb = make_float4(0.f, 0.f, 0.f, 0.f);
    if (bias) bb = *(const float4*)(bias + bn + tn);
    #pragma unroll
    for (int i = 0; i < 4; ++i) {
        float4 c;
        c.x = acc[i][0] + bb.x;
        c.y = acc[i][1] + bb.y;
        c.z = acc[i][2] + bb.z;
        c.w = acc[i][3] + bb.w;
        *(float4*)(C + (long)(bm + tm + i) * ldc + bn + tn) = c;
    }
}

// ---------------- GRU pointwise: in-place h update (elementwise in (b,j))
__global__ __launch_bounds__(256) void gru_pw(const float* __restrict__ gx,
                                              const float* __restrict__ gh,
                                              float* __restrict__ h) {
    const int idx = blockIdx.x * 256 + threadIdx.x;    // [0, B*H)
    const int b = idx >> 9;                            // H_ = 512
    const int j = idx & 511;
    const float* gxr = gx + (long)b * (3 * H_);
    const float* ghr = gh + (long)b * (3 * H_);
    const float xr = gxr[j], xz = gxr[H_ + j], xn = gxr[2 * H_ + j];
    const float hr = ghr[j], hz = ghr[H_ + j], hn = ghr[2 * H_ + j];
    const float r = 1.f / (1.f + expf(-(xr + hr)));
    const float z = 1.f / (1.f + expf(-(xz + hz)));
    const float n = tanhf(xn + r * hn);
    h[idx] = (1.f - z) * n + z * h[idx];
}

// ---------------- softmax over V=1024, in-place on d_out rows, + gumbel
__global__ __launch_bounds__(256) void softmax_k(float* __restrict__ base,
                                                 const float* __restrict__ gum) {
    __shared__ float red[4];
    const int b = blockIdx.x;
    float* p = base + (long)b * OUTLD;
    const float* g = gum + (long)b * V_;
    const int tid = threadIdx.x;
    const float4 lv = *(const float4*)(p + tid * 4);
    const float4 gv = *(const float4*)(g + tid * 4);
    const float x0 = lv.x + gv.x, x1 = lv.y + gv.y;
    const float x2 = lv.z + gv.z, x3 = lv.w + gv.w;
    float m = fmaxf(fmaxf(x0, x1), fmaxf(x2, x3));
    #pragma unroll
    for (int o = 32; o; o >>= 1) m = fmaxf(m, __shfl_xor(m, o));
    if ((tid & 63) == 0) red[tid >> 6] = m;
    __syncthreads();
    m = fmaxf(fmaxf(red[0], red[1]), fmaxf(red[2], red[3]));
    __syncthreads();
    const float e0 = expf(x0 - m), e1 = expf(x1 - m);
    const float e2 = expf(x2 - m), e3 = expf(x3 - m);
    float s = e0 + e1 + e2 + e3;
    #pragma unroll
    for (int o = 32; o; o >>= 1) s += __shfl_xor(s, o);
    if ((tid & 63) == 0) red[tid >> 6] = s;
    __syncthreads();
    s = red[0] + red[1] + red[2] + red[3];
    const float inv = 1.0f / s;
    float4 r;
    r.x = e0 * inv; r.y = e1 * inv; r.z = e2 * inv; r.w = e3 * inv;
    *(float4*)(p + tid * 4) = r;
}

// ---------------- e0 init: broadcast sos
__global__ __launch_bounds__(256) void init_e_k(float* __restrict__ e,
                                                const float* __restrict__ sos) {
    const int idx = blockIdx.x * 256 + threadIdx.x;    // [0, B*E)
    e[idx] = sos[idx & (E_ - 1)];
}

// ---------------- eos row: out[:, L, v] = (v==0)
__global__ __launch_bounds__(256) void eos_k(float* __restrict__ out) {
    const int idx = blockIdx.x * 256 + threadIdx.x;    // [0, B*V)
    const int b = idx >> 10;
    const int v = idx & (V_ - 1);
    out[((long)b * (L_ + 1) + L_) * V_ + v] = (v == 0) ? 1.0f : 0.0f;
}

extern "C" void kernel_launch(void* const* d_in, const int* in_sizes, int n_in,
                              void* d_out, int out_size, void* d_ws, size_t ws_size,
                              hipStream_t stream) {
    const float* x       = (const float*)d_in[0];
    const float* W_agent = (const float*)d_in[1];
    const float* b_agent = (const float*)d_in[2];
    const float* W_ih    = (const float*)d_in[3];
    const float* W_hh    = (const float*)d_in[4];
    const float* b_ih    = (const float*)d_in[5];
    const float* b_hh    = (const float*)d_in[6];
    const float* W_out   = (const float*)d_in[7];
    const float* b_out   = (const float*)d_in[8];
    const float* W_emb   = (const float*)d_in[9];
    const float* b_emb   = (const float*)d_in[10];
    const float* sos     = (const float*)d_in[11];
    const float* gumbel  = (const float*)d_in[12];
    float* out = (float*)d_out;

    float* ws    = (float*)d_ws;
    float* WagT  = ws;                          // [H, DIN]   512*512
    float* WoutT = WagT + DIN_ * H_;            // [V, H]     1024*512
    float* WembT = WoutT + H_ * V_;             // [E, V]     512*1024
    float* h     = WembT + V_ * E_;             // [B, H]
    float* e     = h + (long)B_ * H_;           // [B, E]
    float* gx    = e + (long)B_ * E_;           // [B, 3H]
    float* gh    = gx + (long)B_ * 3 * H_;      // [B, 3H]

    // one-time weight transposes so every GEMM is NT (K contiguous both sides)
    transpose_k<<<dim3(H_ / 32, DIN_ / 32), 256, 0, stream>>>(W_agent, WagT, DIN_, H_);
    transpose_k<<<dim3(V_ / 32, H_ / 32), 256, 0, stream>>>(W_out, WoutT, H_, V_);
    transpose_k<<<dim3(E_ / 32, V_ / 32), 256, 0, stream>>>(W_emb, WembT, V_, E_);

    // h0 = x @ W_agent + b_agent
    gemm_nt<<<dim3(H_ / 64, B_ / 64), 256, 0, stream>>>(x, DIN_, WagT, DIN_, b_agent,
                                                        h, H_, DIN_);
    init_e_k<<<(B_ * E_) / 256, 256, 0, stream>>>(e, sos);
    eos_k<<<(B_ * V_) / 256, 256, 0, stream>>>(out);

    for (int t = 0; t < L_; ++t) {
        // gx = e @ W_ih^T + b_ih   (W_ih is [3H, E] row-major: already NT layout)
        gemm_nt<<<dim3(3 * H_ / 64, B_ / 64), 256, 0, stream>>>(e, E_, W_ih, E_, b_ih,
                                                                gx, 3 * H_, E_);
        // gh = h @ W_hh^T + b_hh
        gemm_nt<<<dim3(3 * H_ / 64, B_ / 64), 256, 0, stream>>>(h, H_, W_hh, H_, b_hh,
                                                                gh, 3 * H_, H_);
        gru_pw<<<(B_ * H_) / 256, 256, 0, stream>>>(gx, gh, h);
        // logits -> d_out[:, t, :]
        float* lg = out + (long)t * V_;
        gemm_nt<<<dim3(V_ / 64, B_ / 64), 256, 0, stream>>>(h, H_, WoutT, H_, b_out,
                                                            lg, OUTLD, H_);
        // in-place softmax((logits+gumbel)/1.0) on d_out rows
        softmax_k<<<B_, 256, 0, stream>>>(lg, gumbel + (long)t * B_ * V_);
        // e = sample @ W_emb + b_emb  (reads samples back from d_out)
        gemm_nt<<<dim3(E_ / 64, B_ / 64), 256, 0, stream>>>(lg, OUTLD, WembT, V_, b_emb,
                                                            e, E_, V_);
    }
}

// Round 6
// 2189.603 us; speedup vs baseline: 3.0881x; 3.0881x over previous
//
#include <hip/hip_runtime.h>
#include <math.h>

#define B_   2048
#define DIN_ 512
#define H_   512
#define E_   512
#define V_   1024
#define L_   32
#define OUTLD (33 * 1024)   // fp32 row stride of d_out per batch element

typedef unsigned short u16;
typedef __attribute__((ext_vector_type(8))) __bf16 bf16x8;
typedef __attribute__((ext_vector_type(4))) float f32x4;

// fp32 -> bf16 round-to-nearest-even
__device__ __forceinline__ u16 f2bf(float f) {
    unsigned u = __float_as_uint(f);
    return (u16)((u + 0x7fffu + ((u >> 16) & 1u)) >> 16);
}

// async global->LDS, 16 bytes per lane, wave-uniform LDS base
__device__ __forceinline__ void gload16(const u16* g, u16* l) {
    __builtin_amdgcn_global_load_lds(
        (const __attribute__((address_space(1))) void*)g,
        (__attribute__((address_space(3))) void*)l, 16, 0, 0);
}

// ---------------- one-time converters ----------------
// straight fp32 -> bf16, 4 elems/thread
__global__ __launch_bounds__(256) void cvt4_k(const float* __restrict__ s,
                                              u16* __restrict__ d) {
    const int i = (blockIdx.x * 256 + threadIdx.x) * 4;
    const float4 v = *(const float4*)(s + i);
    *(ushort4*)(d + i) = make_ushort4(f2bf(v.x), f2bf(v.y), f2bf(v.z), f2bf(v.w));
}

// transpose + convert: src [R][C] fp32 -> dst [C][R] bf16
__global__ __launch_bounds__(256) void cvtT_k(const float* __restrict__ src,
                                              u16* __restrict__ dst, int R, int C) {
    __shared__ float t[32][33];
    const int bc = blockIdx.x * 32, br = blockIdx.y * 32;
    const int tx = threadIdx.x & 31, ty = threadIdx.x >> 5;
    #pragma unroll
    for (int i = 0; i < 32; i += 8)
        t[ty + i][tx] = src[(long)(br + ty + i) * C + bc + tx];
    __syncthreads();
    #pragma unroll
    for (int i = 0; i < 32; i += 8)
        dst[(long)(bc + ty + i) * R + br + tx] = f2bf(t[tx][ty + i]);
}

// ---------------- bf16 MFMA GEMM: C[M,N] = A[M,K] * B[N,K]^T + bias[N] ----------------
// A, B bf16 (K-contiguous both sides). Tile BM x BN, BK=32, 256 threads (4 waves 2x2),
// wave subtile (BM/2)x(BN/2), 16x16x32 MFMA, fp32 accum. Optional fp32 and/or bf16 C.
template<int BM, int BN, bool WF32, bool WBF16>
__device__ __forceinline__ void gemm_body(const u16* __restrict__ A, int lda,
                                          const u16* __restrict__ Bm, int ldb,
                                          const float* __restrict__ bias,
                                          float* __restrict__ C, long ldc,
                                          u16* __restrict__ Cb, int ldcb, int K) {
    constexpr int MR = BM / 32, NR = BN / 32;
    __shared__ __align__(16) u16 As[BM][32];
    __shared__ __align__(16) u16 Bs[BN][32];
    const int tid = threadIdx.x;
    const int w = tid >> 6, l = tid & 63;
    const int wr = w >> 1, wc = w & 1;
    const int bm = blockIdx.y * BM, bn = blockIdx.x * BN;
    const int srow = l >> 2;            // 0..15 row within a 16-row staging group
    const int skoff = (l & 3) * 8;      // 0,8,16,24 bf16 k-offset

    f32x4 zero = {0.f, 0.f, 0.f, 0.f};
    f32x4 acc[MR][NR];
    #pragma unroll
    for (int i = 0; i < MR; ++i)
        #pragma unroll
        for (int j = 0; j < NR; ++j) acc[i][j] = zero;

    const u16* Abase = A + (long)bm * lda + skoff;
    const u16* Bbase = Bm + (long)bn * ldb + skoff;

    for (int k0 = 0; k0 < K; k0 += 32) {
        __syncthreads();   // previous tile fully consumed
        #pragma unroll
        for (int i = 0; i < BM / 64; ++i) {
            const int r = w * (BM / 4) + i * 16;   // wave-uniform LDS row base
            gload16(Abase + (long)(r + srow) * lda + k0, &As[r][0]);
        }
        #pragma unroll
        for (int i = 0; i < BN / 64; ++i) {
            const int r = w * (BN / 4) + i * 16;
            gload16(Bbase + (long)(r + srow) * ldb + k0, &Bs[r][0]);
        }
        __syncthreads();   // staged (compiler drains vmcnt before barrier)

        bf16x8 af[MR], bfr[NR];
        #pragma unroll
        for (int mi = 0; mi < MR; ++mi)
            af[mi] = *(const bf16x8*)&As[wr * (BM / 2) + mi * 16 + (l & 15)][(l >> 4) * 8];
        #pragma unroll
        for (int ni = 0; ni < NR; ++ni)
            bfr[ni] = *(const bf16x8*)&Bs[wc * (BN / 2) + ni * 16 + (l & 15)][(l >> 4) * 8];
        #pragma unroll
        for (int mi = 0; mi < MR; ++mi)
            #pragma unroll
            for (int ni = 0; ni < NR; ++ni)
                acc[mi][ni] = __builtin_amdgcn_mfma_f32_16x16x32_bf16(
                    af[mi], bfr[ni], acc[mi][ni], 0, 0, 0);
    }

    // epilogue: C[row][col], row=(l>>4)*4+reg, col=l&15 (m89-verified layout)
    #pragma unroll
    for (int mi = 0; mi < MR; ++mi) {
        const int row0 = bm + wr * (BM / 2) + mi * 16 + (l >> 4) * 4;
        #pragma unroll
        for (int ni = 0; ni < NR; ++ni) {
            const int col = bn + wc * (BN / 2) + ni * 16 + (l & 15);
            const float bb = bias[col];
            #pragma unroll
            for (int r = 0; r < 4; ++r) {
                const float v = acc[mi][ni][r] + bb;
                if constexpr (WF32) C[(long)(row0 + r) * ldc + col] = v;
                if constexpr (WBF16) Cb[(long)(row0 + r) * ldcb + col] = f2bf(v);
            }
        }
    }
}

template<int BM, int BN, bool WF32, bool WBF16>
__global__ __launch_bounds__(256) void gemm_k(const u16* __restrict__ A, int lda,
                                              const u16* __restrict__ Bm, int ldb,
                                              const float* __restrict__ bias,
                                              float* __restrict__ C, long ldc,
                                              u16* __restrict__ Cb, int ldcb, int K) {
    gemm_body<BM, BN, WF32, WBF16>(A, lda, Bm, ldb, bias, C, ldc, Cb, ldcb, K);
}

// fused gx/gh: blockIdx.z picks {e,W_ih,b_ih,gx} vs {h,W_hh,b_hh,gh}; same shapes
__global__ __launch_bounds__(256) void gemm_dual_k(const u16* __restrict__ e_b,
                                                   const u16* __restrict__ h_b,
                                                   const u16* __restrict__ Wih,
                                                   const u16* __restrict__ Whh,
                                                   const float* __restrict__ b_ih,
                                                   const float* __restrict__ b_hh,
                                                   float* __restrict__ gx,
                                                   float* __restrict__ gh) {
    const bool z = blockIdx.z != 0;
    gemm_body<128, 128, true, false>(z ? h_b : e_b, H_, z ? Whh : Wih, H_,
                                     z ? b_hh : b_ih, z ? gh : gx, 3 * H_,
                                     (u16*)nullptr, 0, H_);
}

// ---------------- GRU pointwise: in-place fp32 h update + bf16 copy ----------------
__global__ __launch_bounds__(256) void gru_pw(const float* __restrict__ gx,
                                              const float* __restrict__ gh,
                                              float* __restrict__ h,
                                              u16* __restrict__ hb) {
    const int i4 = (blockIdx.x * 256 + threadIdx.x) * 4;   // over B*H
    const int b = i4 >> 9, j = i4 & 511;
    const float* gxr = gx + (long)b * 1536 + j;
    const float* ghr = gh + (long)b * 1536 + j;
    const float4 xr = *(const float4*)gxr;
    const float4 xz = *(const float4*)(gxr + 512);
    const float4 xn = *(const float4*)(gxr + 1024);
    const float4 hr = *(const float4*)ghr;
    const float4 hz = *(const float4*)(ghr + 512);
    const float4 hn = *(const float4*)(ghr + 1024);
    float4 hv = *(const float4*)(h + i4);
#define GRU1(c) { \
        const float r_ = 1.f / (1.f + __expf(-(xr.c + hr.c))); \
        const float z_ = 1.f / (1.f + __expf(-(xz.c + hz.c))); \
        const float t_ = xn.c + r_ * hn.c; \
        const float n_ = 1.f - 2.f / (__expf(2.f * t_) + 1.f); \
        hv.c = (1.f - z_) * n_ + z_ * hv.c; }
    GRU1(x) GRU1(y) GRU1(z) GRU1(w)
#undef GRU1
    *(float4*)(h + i4) = hv;
    *(ushort4*)(hb + i4) = make_ushort4(f2bf(hv.x), f2bf(hv.y), f2bf(hv.z), f2bf(hv.w));
}

// ---------------- softmax over V=1024 in-place on d_out + bf16 sample copy ----------------
__global__ __launch_bounds__(256) void softmax_k(float* __restrict__ base,
                                                 const float* __restrict__ gum,
                                                 u16* __restrict__ sb) {
    __shared__ float red[4];
    const int b = blockIdx.x;
    float* p = base + (long)b * OUTLD;
    const float* g = gum + (long)b * V_;
    const int tid = threadIdx.x;
    const float4 lv = *(const float4*)(p + tid * 4);
    const float4 gv = *(const float4*)(g + tid * 4);
    const float x0 = lv.x + gv.x, x1 = lv.y + gv.y;
    const float x2 = lv.z + gv.z, x3 = lv.w + gv.w;
    float m = fmaxf(fmaxf(x0, x1), fmaxf(x2, x3));
    #pragma unroll
    for (int o = 32; o; o >>= 1) m = fmaxf(m, __shfl_xor(m, o));
    if ((tid & 63) == 0) red[tid >> 6] = m;
    __syncthreads();
    m = fmaxf(fmaxf(red[0], red[1]), fmaxf(red[2], red[3]));
    __syncthreads();
    const float e0 = __expf(x0 - m), e1 = __expf(x1 - m);
    const float e2 = __expf(x2 - m), e3 = __expf(x3 - m);
    float s = e0 + e1 + e2 + e3;
    #pragma unroll
    for (int o = 32; o; o >>= 1) s += __shfl_xor(s, o);
    if ((tid & 63) == 0) red[tid >> 6] = s;
    __syncthreads();
    s = red[0] + red[1] + red[2] + red[3];
    const float inv = 1.0f / s;
    float4 r;
    r.x = e0 * inv; r.y = e1 * inv; r.z = e2 * inv; r.w = e3 * inv;
    *(float4*)(p + tid * 4) = r;
    *(ushort4*)(sb + (long)b * V_ + tid * 4) =
        make_ushort4(f2bf(r.x), f2bf(r.y), f2bf(r.z), f2bf(r.w));
}

// ---------------- e0 = broadcast(sos) in bf16 ----------------
__global__ __launch_bounds__(256) void init_e_b(u16* __restrict__ eb,
                                                const float* __restrict__ sos) {
    const int idx = blockIdx.x * 256 + threadIdx.x;
    eb[idx] = f2bf(sos[idx & (E_ - 1)]);
}

// ---------------- eos row: out[:, L, v] = (v==0) ----------------
__global__ __launch_bounds__(256) void eos_k(float* __restrict__ out) {
    const int idx = blockIdx.x * 256 + threadIdx.x;
    const int b = idx >> 10;
    const int v = idx & (V_ - 1);
    out[((long)b * (L_ + 1) + L_) * V_ + v] = (v == 0) ? 1.0f : 0.0f;
}

extern "C" void kernel_launch(void* const* d_in, const int* in_sizes, int n_in,
                              void* d_out, int out_size, void* d_ws, size_t ws_size,
                              hipStream_t stream) {
    const float* x       = (const float*)d_in[0];
    const float* W_agent = (const float*)d_in[1];
    const float* b_agent = (const float*)d_in[2];
    const float* W_ih    = (const float*)d_in[3];
    const float* W_hh    = (const float*)d_in[4];
    const float* b_ih    = (const float*)d_in[5];
    const float* b_hh    = (const float*)d_in[6];
    const float* W_out   = (const float*)d_in[7];
    const float* b_out   = (const float*)d_in[8];
    const float* W_emb   = (const float*)d_in[9];
    const float* b_emb   = (const float*)d_in[10];
    const float* sos     = (const float*)d_in[11];
    const float* gumbel  = (const float*)d_in[12];
    float* out = (float*)d_out;

    // workspace layout (bf16 region first, then fp32)
    u16* WagT_b  = (u16*)d_ws;                      // [H][DIN]   262144
    u16* Wih_b   = WagT_b  + H_ * DIN_;             // [3H][E]    786432
    u16* Whh_b   = Wih_b   + 3 * H_ * E_;           // [3H][H]    786432
    u16* WoutT_b = Whh_b   + 3 * H_ * H_;           // [V][H]     524288
    u16* WembT_b = WoutT_b + V_ * H_;               // [E][V]     524288
    u16* x_b     = WembT_b + E_ * V_;               // [B][DIN]  1048576
    u16* h_b     = x_b     + (long)B_ * DIN_;       // [B][H]
    u16* e_b     = h_b     + (long)B_ * H_;         // [B][E]
    u16* samp_b  = e_b     + (long)B_ * E_;         // [B][V]
    float* h     = (float*)(samp_b + (long)B_ * V_);// [B][H] fp32 master
    float* gx    = h  + (long)B_ * H_;              // [B][3H]
    float* gh    = gx + (long)B_ * 3 * H_;          // [B][3H]

    // one-time weight conversions (bf16, K-contiguous NT layouts)
    cvtT_k<<<dim3(H_ / 32, DIN_ / 32), 256, 0, stream>>>(W_agent, WagT_b, DIN_, H_);
    cvt4_k<<<(3 * H_ * E_) / 1024, 256, 0, stream>>>(W_ih, Wih_b);
    cvt4_k<<<(3 * H_ * H_) / 1024, 256, 0, stream>>>(W_hh, Whh_b);
    cvtT_k<<<dim3(V_ / 32, H_ / 32), 256, 0, stream>>>(W_out, WoutT_b, H_, V_);
    cvtT_k<<<dim3(E_ / 32, V_ / 32), 256, 0, stream>>>(W_emb, WembT_b, V_, E_);
    cvt4_k<<<((long)B_ * DIN_) / 1024, 256, 0, stream>>>(x, x_b);

    // h0 = x @ W_agent + b_agent  (fp32 master + bf16 copy)
    gemm_k<64, 64, true, true><<<dim3(H_ / 64, B_ / 64), 256, 0, stream>>>(
        x_b, DIN_, WagT_b, DIN_, b_agent, h, H_, h_b, H_, DIN_);
    init_e_b<<<(B_ * E_) / 256, 256, 0, stream>>>(e_b, sos);
    eos_k<<<(B_ * V_) / 256, 256, 0, stream>>>(out);

    for (int t = 0; t < L_; ++t) {
        // gx = e @ W_ih^T + b_ih ; gh = h @ W_hh^T + b_hh  (fused, z selects)
        gemm_dual_k<<<dim3(3 * H_ / 128, B_ / 128, 2), 256, 0, stream>>>(
            e_b, h_b, Wih_b, Whh_b, b_ih, b_hh, gx, gh);
        gru_pw<<<((long)B_ * H_) / 1024, 256, 0, stream>>>(gx, gh, h, h_b);
        // logits -> d_out[:, t, :]
        float* lg = out + (long)t * V_;
        gemm_k<128, 64, true, false><<<dim3(V_ / 64, B_ / 128), 256, 0, stream>>>(
            h_b, H_, WoutT_b, H_, b_out, lg, OUTLD, (u16*)nullptr, 0, H_);
        // softmax((logits+gumbel)/T) in-place + bf16 sample
        softmax_k<<<B_, 256, 0, stream>>>(lg, gumbel + (long)t * B_ * V_, samp_b);
        // e = sample @ W_emb + b_emb  (bf16 out only)
        gemm_k<64, 64, false, true><<<dim3(E_ / 64, B_ / 64), 256, 0, stream>>>(
            samp_b, V_, WembT_b, V_, b_emb, (float*)nullptr, 0, e_b, E_, V_);
    }
}

// Round 8
// 1891.727 us; speedup vs baseline: 3.5743x; 1.1575x over previous
//
#include <hip/hip_runtime.h>
#include <math.h>

#define B_   2048
#define DIN_ 512
#define H_   512
#define E_   512
#define V_   1024
#define L_   32
#define OUTLD (33 * 1024)   // fp32 row stride of d_out per batch element

typedef unsigned short u16;
typedef __attribute__((ext_vector_type(8))) __bf16 bf16x8;
typedef __attribute__((ext_vector_type(4))) float f32x4;

// fp32 -> bf16 round-to-nearest-even
__device__ __forceinline__ u16 f2bf(float f) {
    unsigned u = __float_as_uint(f);
    return (u16)((u + 0x7fffu + ((u >> 16) & 1u)) >> 16);
}

// async global->LDS, 16 bytes per lane, wave-uniform LDS base
__device__ __forceinline__ void gload16(const u16* g, u16* l) {
    __builtin_amdgcn_global_load_lds(
        (const __attribute__((address_space(1))) void*)g,
        (__attribute__((address_space(3))) void*)l, 16, 0, 0);
}

// ---------------- one-time converters ----------------
__global__ __launch_bounds__(256) void cvt4_k(const float* __restrict__ s,
                                              u16* __restrict__ d) {
    const int i = (blockIdx.x * 256 + threadIdx.x) * 4;
    const float4 v = *(const float4*)(s + i);
    *(ushort4*)(d + i) = make_ushort4(f2bf(v.x), f2bf(v.y), f2bf(v.z), f2bf(v.w));
}

// transpose + convert: src [R][C] fp32 -> dst [C][R] bf16
__global__ __launch_bounds__(256) void cvtT_k(const float* __restrict__ src,
                                              u16* __restrict__ dst, int R, int C) {
    __shared__ float t[32][33];
    const int bc = blockIdx.x * 32, br = blockIdx.y * 32;
    const int tx = threadIdx.x & 31, ty = threadIdx.x >> 5;
    #pragma unroll
    for (int i = 0; i < 32; i += 8)
        t[ty + i][tx] = src[(long)(br + ty + i) * C + bc + tx];
    __syncthreads();
    #pragma unroll
    for (int i = 0; i < 32; i += 8)
        dst[(long)(bc + ty + i) * R + br + tx] = f2bf(t[tx][ty + i]);
}

// pack W_ih/W_hh (fp32 [3H][512]) -> Wcomb bf16 [16 tiles][192 rows][512]
// tile T covers hidden cols [T*32, T*32+32); rows: g*32+r, g=0..2 -> W_ih gate g,
// g=3..5 -> W_hh gate g-3; row r within tile.
__global__ __launch_bounds__(256) void pack_w_k(const float* __restrict__ Wih,
                                                const float* __restrict__ Whh,
                                                u16* __restrict__ dst) {
    const long idx = ((long)blockIdx.x * 256 + threadIdx.x) * 4;  // 16*192*512 total
    const int k = (int)(idx & 511);
    const int rowid = (int)(idx >> 9);      // 0 .. 16*192
    const int gr = rowid % 192;
    const int t = rowid / 192;
    const int g = gr >> 5, r = gr & 31;
    const float* src = (g < 3)
        ? Wih + ((long)(g * H_ + t * 32 + r) << 9)
        : Whh + ((long)((g - 3) * H_ + t * 32 + r) << 9);
    const float4 v = *(const float4*)(src + k);
    *(ushort4*)(dst + idx) = make_ushort4(f2bf(v.x), f2bf(v.y), f2bf(v.z), f2bf(v.w));
}

// ---------------- bf16 MFMA GEMM (prefetch double-buffered) ----------------
// C[M,N] = A[M,K]*B[N,K]^T + bias[N]. BK=32, 256 threads (4 waves 2x2).
template<int BM, int BN, bool WF32, bool WBF16>
__device__ __forceinline__ void gemm_body(const u16* __restrict__ A, int lda,
                                          const u16* __restrict__ Bm, int ldb,
                                          const float* __restrict__ bias,
                                          float* __restrict__ C, long ldc,
                                          u16* __restrict__ Cb, int ldcb, int K) {
    constexpr int MR = BM / 32, NR = BN / 32;
    __shared__ __align__(16) u16 As[2][BM][32];
    __shared__ __align__(16) u16 Bs[2][BN][32];
    const int tid = threadIdx.x;
    const int w = tid >> 6, l = tid & 63;
    const int wr = w >> 1, wc = w & 1;
    const int bm = blockIdx.y * BM, bn = blockIdx.x * BN;
    const int srow = l >> 2;
    const int skoff = (l & 3) * 8;

    f32x4 acc[MR][NR];
    #pragma unroll
    for (int i = 0; i < MR; ++i)
        #pragma unroll
        for (int j = 0; j < NR; ++j) acc[i][j] = {0.f, 0.f, 0.f, 0.f};

    const u16* Abase = A + (long)bm * lda + skoff;
    const u16* Bbase = Bm + (long)bn * ldb + skoff;

    auto stage = [&](int buf, int k0) {
        #pragma unroll
        for (int i = 0; i < BM / 64; ++i) {
            const int r = w * (BM / 4) + i * 16;
            gload16(Abase + (long)(r + srow) * lda + k0, &As[buf][r][0]);
        }
        #pragma unroll
        for (int i = 0; i < BN / 64; ++i) {
            const int r = w * (BN / 4) + i * 16;
            gload16(Bbase + (long)(r + srow) * ldb + k0, &Bs[buf][r][0]);
        }
    };
    auto compute = [&](int buf) {
        bf16x8 af[MR], bfr[NR];
        #pragma unroll
        for (int mi = 0; mi < MR; ++mi)
            af[mi] = *(const bf16x8*)&As[buf][wr * (BM / 2) + mi * 16 + (l & 15)][(l >> 4) * 8];
        #pragma unroll
        for (int ni = 0; ni < NR; ++ni)
            bfr[ni] = *(const bf16x8*)&Bs[buf][wc * (BN / 2) + ni * 16 + (l & 15)][(l >> 4) * 8];
        #pragma unroll
        for (int mi = 0; mi < MR; ++mi)
            #pragma unroll
            for (int ni = 0; ni < NR; ++ni)
                acc[mi][ni] = __builtin_amdgcn_mfma_f32_16x16x32_bf16(
                    af[mi], bfr[ni], acc[mi][ni], 0, 0, 0);
    };

    // prefetch pipeline: stage(t+1) overlaps compute(t); one barrier per tile
    stage(0, 0);
    __syncthreads();
    int cur = 0;
    for (int k0 = 32; k0 < K; k0 += 32) {
        stage(cur ^ 1, k0);
        compute(cur);
        __syncthreads();      // drains vmcnt (stage done) + lgkm; syncs waves
        cur ^= 1;
    }
    compute(cur);

    #pragma unroll
    for (int mi = 0; mi < MR; ++mi) {
        const int row0 = bm + wr * (BM / 2) + mi * 16 + (l >> 4) * 4;
        #pragma unroll
        for (int ni = 0; ni < NR; ++ni) {
            const int col = bn + wc * (BN / 2) + ni * 16 + (l & 15);
            const float bb = bias[col];
            #pragma unroll
            for (int r = 0; r < 4; ++r) {
                const float v = acc[mi][ni][r] + bb;
                if constexpr (WF32) C[(long)(row0 + r) * ldc + col] = v;
                if constexpr (WBF16) Cb[(long)(row0 + r) * ldcb + col] = f2bf(v);
            }
        }
    }
}

template<int BM, int BN, bool WF32, bool WBF16>
__global__ __launch_bounds__(256) void gemm_k(const u16* __restrict__ A, int lda,
                                              const u16* __restrict__ Bm, int ldb,
                                              const float* __restrict__ bias,
                                              float* __restrict__ C, long ldc,
                                              u16* __restrict__ Cb, int ldcb, int K) {
    gemm_body<BM, BN, WF32, WBF16>(A, lda, Bm, ldb, bias, C, ldc, Cb, ldcb, K);
}

// ---------------- fused GRU step: 6 gate-GEMMs + pointwise, one kernel ----------------
// Block: 64 batch rows x 32 hidden cols. Computes (e@Wih^T) and (h@Whh^T) for
// r,z,n gates on this tile (K=512 each), then the GRU update in-register.
// h/h_b double-buffered across steps (in != out).
__global__ __launch_bounds__(256) void gru_gemm_k(
    const u16* __restrict__ e_b,      // [B][512] bf16
    const u16* __restrict__ hb_in,    // [B][512] bf16
    const float* __restrict__ h_in,   // [B][512] fp32
    const u16* __restrict__ Wcomb,    // [16][192][512] bf16 packed
    const float* __restrict__ b_ih, const float* __restrict__ b_hh,
    float* __restrict__ h_out, u16* __restrict__ hb_out) {
    __shared__ __align__(16) u16 lds[2][320][32];  // rows: 0-63 e, 64-127 h, 128-319 W
    const int tid = threadIdx.x;
    const int w = tid >> 6, l = tid & 63;
    const int wr = w >> 1, wc = w & 1;
    const int bn = blockIdx.x * 32;
    const int bm = blockIdx.y * 64;
    const int srow = l >> 2;
    const int skoff = (l & 3) * 8;
    const u16* WT = Wcomb + (long)blockIdx.x * 192 * 512;

    f32x4 ax[3][2], ah[3][2];
    #pragma unroll
    for (int g = 0; g < 3; ++g)
        #pragma unroll
        for (int mi = 0; mi < 2; ++mi) {
            ax[g][mi] = {0.f, 0.f, 0.f, 0.f};
            ah[g][mi] = {0.f, 0.f, 0.f, 0.f};
        }

    auto stage = [&](int buf, int k0) {
        #pragma unroll
        for (int i = 0; i < 5; ++i) {
            const int c = w * 5 + i;   // 20 calls cover 320 LDS rows
            const u16* src;
            if (c < 4)      src = e_b   + (long)(bm + c * 16 + srow) * 512;
            else if (c < 8) src = hb_in + (long)(bm + (c - 4) * 16 + srow) * 512;
            else            src = WT    + (long)((c - 8) * 16 + srow) * 512;
            gload16(src + k0 + skoff, &lds[buf][c * 16][0]);
        }
    };
    auto compute = [&](int buf) {
        bf16x8 ae[2], ahf[2], bf[6];
        #pragma unroll
        for (int mi = 0; mi < 2; ++mi) {
            ae[mi]  = *(const bf16x8*)&lds[buf][wr * 32 + mi * 16 + (l & 15)][(l >> 4) * 8];
            ahf[mi] = *(const bf16x8*)&lds[buf][64 + wr * 32 + mi * 16 + (l & 15)][(l >> 4) * 8];
        }
        #pragma unroll
        for (int g = 0; g < 6; ++g)
            bf[g] = *(const bf16x8*)&lds[buf][128 + g * 32 + wc * 16 + (l & 15)][(l >> 4) * 8];
        #pragma unroll
        for (int g = 0; g < 3; ++g)
            #pragma unroll
            for (int mi = 0; mi < 2; ++mi) {
                ax[g][mi] = __builtin_amdgcn_mfma_f32_16x16x32_bf16(ae[mi],  bf[g],     ax[g][mi], 0, 0, 0);
                ah[g][mi] = __builtin_amdgcn_mfma_f32_16x16x32_bf16(ahf[mi], bf[3 + g], ah[g][mi], 0, 0, 0);
            }
    };

    stage(0, 0);
    __syncthreads();
    int cur = 0;
    for (int k0 = 32; k0 < 512; k0 += 32) {
        stage(cur ^ 1, k0);
        compute(cur);
        __syncthreads();
        cur ^= 1;
    }
    compute(cur);

    const int col = bn + wc * 16 + (l & 15);
    const float bxr = b_ih[col], bxz = b_ih[512 + col], bxn = b_ih[1024 + col];
    const float bhr = b_hh[col], bhz = b_hh[512 + col], bhn = b_hh[1024 + col];
    #pragma unroll
    for (int mi = 0; mi < 2; ++mi) {
        const int row0 = bm + wr * 32 + mi * 16 + (l >> 4) * 4;
        #pragma unroll
        for (int r = 0; r < 4; ++r) {
            const long off = (long)(row0 + r) * 512 + col;
            const float xr = ax[0][mi][r] + bxr, hr = ah[0][mi][r] + bhr;
            const float xz = ax[1][mi][r] + bxz, hz = ah[1][mi][r] + bhz;
            const float xn = ax[2][mi][r] + bxn, hn = ah[2][mi][r] + bhn;
            const float r_ = 1.f / (1.f + __expf(-(xr + hr)));
            const float z_ = 1.f / (1.f + __expf(-(xz + hz)));
            const float t_ = xn + r_ * hn;
            const float n_ = 1.f - 2.f / (__expf(2.f * t_) + 1.f);
            const float hv = (1.f - z_) * n_ + z_ * h_in[off];
            h_out[off] = hv;
            hb_out[off] = f2bf(hv);
        }
    }
}

// ---------------- softmax over V=1024 in-place on d_out + bf16 sample copy ----------------
__global__ __launch_bounds__(256) void softmax_k(float* __restrict__ base,
                                                 const float* __restrict__ gum,
                                                 u16* __restrict__ sb) {
    __shared__ float red[4];
    const int b = blockIdx.x;
    float* p = base + (long)b * OUTLD;
    const float* g = gum + (long)b * V_;
    const int tid = threadIdx.x;
    const float4 lv = *(const float4*)(p + tid * 4);
    const float4 gv = *(const float4*)(g + tid * 4);
    const float x0 = lv.x + gv.x, x1 = lv.y + gv.y;
    const float x2 = lv.z + gv.z, x3 = lv.w + gv.w;
    float m = fmaxf(fmaxf(x0, x1), fmaxf(x2, x3));
    #pragma unroll
    for (int o = 32; o; o >>= 1) m = fmaxf(m, __shfl_xor(m, o));
    if ((tid & 63) == 0) red[tid >> 6] = m;
    __syncthreads();
    m = fmaxf(fmaxf(red[0], red[1]), fmaxf(red[2], red[3]));
    __syncthreads();
    const float e0 = __expf(x0 - m), e1 = __expf(x1 - m);
    const float e2 = __expf(x2 - m), e3 = __expf(x3 - m);
    float s = e0 + e1 + e2 + e3;
    #pragma unroll
    for (int o = 32; o; o >>= 1) s += __shfl_xor(s, o);
    if ((tid & 63) == 0) red[tid >> 6] = s;
    __syncthreads();
    s = red[0] + red[1] + red[2] + red[3];
    const float inv = 1.0f / s;
    float4 r;
    r.x = e0 * inv; r.y = e1 * inv; r.z = e2 * inv; r.w = e3 * inv;
    *(float4*)(p + tid * 4) = r;
    *(ushort4*)(sb + (long)b * V_ + tid * 4) =
        make_ushort4(f2bf(r.x), f2bf(r.y), f2bf(r.z), f2bf(r.w));
}

// ---------------- e0 = broadcast(sos) bf16 ----------------
__global__ __launch_bounds__(256) void init_e_b(u16* __restrict__ eb,
                                                const float* __restrict__ sos) {
    const int idx = blockIdx.x * 256 + threadIdx.x;
    eb[idx] = f2bf(sos[idx & (E_ - 1)]);
}

// ---------------- eos row ----------------
__global__ __launch_bounds__(256) void eos_k(float* __restrict__ out) {
    const int idx = blockIdx.x * 256 + threadIdx.x;
    const int b = idx >> 10;
    const int v = idx & (V_ - 1);
    out[((long)b * (L_ + 1) + L_) * V_ + v] = (v == 0) ? 1.0f : 0.0f;
}

extern "C" void kernel_launch(void* const* d_in, const int* in_sizes, int n_in,
                              void* d_out, int out_size, void* d_ws, size_t ws_size,
                              hipStream_t stream) {
    const float* x       = (const float*)d_in[0];
    const float* W_agent = (const float*)d_in[1];
    const float* b_agent = (const float*)d_in[2];
    const float* W_ih    = (const float*)d_in[3];
    const float* W_hh    = (const float*)d_in[4];
    const float* b_ih    = (const float*)d_in[5];
    const float* b_hh    = (const float*)d_in[6];
    const float* W_out   = (const float*)d_in[7];
    const float* b_out   = (const float*)d_in[8];
    const float* W_emb   = (const float*)d_in[9];
    const float* b_emb   = (const float*)d_in[10];
    const float* sos     = (const float*)d_in[11];
    const float* gumbel  = (const float*)d_in[12];
    float* out = (float*)d_out;

    // workspace layout: bf16 region, then fp32
    u16* WagT_b  = (u16*)d_ws;                       // [H][DIN]      262144
    u16* Wcomb   = WagT_b  + H_ * DIN_;              // [16][192][512] 1572864
    u16* WoutT_b = Wcomb   + 16 * 192 * 512;         // [V][H]        524288
    u16* WembT_b = WoutT_b + V_ * H_;                // [E][V]        524288
    u16* x_b     = WembT_b + E_ * V_;                // [B][DIN]     1048576
    u16* hb0     = x_b     + (long)B_ * DIN_;        // [B][H]
    u16* hb1     = hb0     + (long)B_ * H_;          // [B][H]
    u16* e_b     = hb1     + (long)B_ * H_;          // [B][E]
    u16* samp_b  = e_b     + (long)B_ * E_;          // [B][V]
    float* h0    = (float*)(samp_b + (long)B_ * V_); // [B][H] fp32
    float* h1    = h0 + (long)B_ * H_;               // [B][H] fp32

    // one-time weight conversions
    cvtT_k<<<dim3(H_ / 32, DIN_ / 32), 256, 0, stream>>>(W_agent, WagT_b, DIN_, H_);
    pack_w_k<<<(16 * 192 * 512) / 1024, 256, 0, stream>>>(W_ih, W_hh, Wcomb);
    cvtT_k<<<dim3(V_ / 32, H_ / 32), 256, 0, stream>>>(W_out, WoutT_b, H_, V_);
    cvtT_k<<<dim3(E_ / 32, V_ / 32), 256, 0, stream>>>(W_emb, WembT_b, V_, E_);
    cvt4_k<<<((long)B_ * DIN_) / 1024, 256, 0, stream>>>(x, x_b);

    // h0 = x @ W_agent + b_agent (fp32 + bf16)
    gemm_k<64, 64, true, true><<<dim3(H_ / 64, B_ / 64), 256, 0, stream>>>(
        x_b, DIN_, WagT_b, DIN_, b_agent, h0, H_, hb0, H_, DIN_);
    init_e_b<<<(B_ * E_) / 256, 256, 0, stream>>>(e_b, sos);
    eos_k<<<(B_ * V_) / 256, 256, 0, stream>>>(out);

    for (int t = 0; t < L_; ++t) {
        const bool even = (t & 1) == 0;
        const u16* hbi = even ? hb0 : hb1;
        u16* hbo       = even ? hb1 : hb0;
        const float* hi = even ? h0 : h1;
        float* ho       = even ? h1 : h0;
        // fused: 6 gate GEMMs + GRU pointwise -> h_new (fp32+bf16)
        gru_gemm_k<<<dim3(H_ / 32, B_ / 64), 256, 0, stream>>>(
            e_b, hbi, hi, Wcomb, b_ih, b_hh, ho, hbo);
        // logits -> d_out[:, t, :]
        float* lg = out + (long)t * V_;
        gemm_k<128, 64, true, false><<<dim3(V_ / 64, B_ / 128), 256, 0, stream>>>(
            hbo, H_, WoutT_b, H_, b_out, lg, OUTLD, (u16*)nullptr, 0, H_);
        // softmax((logits+gumbel)/T) in-place + bf16 sample
        softmax_k<<<B_, 256, 0, stream>>>(lg, gumbel + (long)t * B_ * V_, samp_b);
        // e = sample @ W_emb + b_emb (bf16 out)
        gemm_k<64, 64, false, true><<<dim3(E_ / 64, B_ / 64), 256, 0, stream>>>(
            samp_b, V_, WembT_b, V_, b_emb, (float*)nullptr, 0, e_b, E_, V_);
    }
}